// Round 2
// baseline (452.019 us; speedup 1.0000x reference)
//
#include <hip/hip_runtime.h>
#include <cstdint>
#include <cstddef>

// ---- types ----
typedef unsigned short u16;
typedef float  f32x4  __attribute__((ext_vector_type(4)));
typedef __bf16 bf16x8 __attribute__((ext_vector_type(8)));
typedef unsigned short us8 __attribute__((ext_vector_type(8)));
typedef unsigned short us4 __attribute__((ext_vector_type(4)));
typedef float  f32x4v __attribute__((ext_vector_type(4)));

#define AS1 __attribute__((address_space(1)))
#define AS3 __attribute__((address_space(3)))

// fp32 -> bf16 round-to-nearest-even
__device__ __forceinline__ u16 f2b(float f) {
  unsigned u = __float_as_uint(f);
  u += 0x7FFFu + ((u >> 16) & 1u);
  return (u16)(u >> 16);
}

__device__ __forceinline__ bf16x8 ldfrag(const u16* p) {
  us8 v = *(const us8*)p;
  return __builtin_bit_cast(bf16x8, v);
}

__device__ __forceinline__ f32x4 mfma16(bf16x8 a, bf16x8 b, f32x4 c) {
  return __builtin_amdgcn_mfma_f32_16x16x32_bf16(a, b, c, 0, 0, 0);
}

// async global->LDS, 16B per lane; lds base must be wave-uniform (lane*16 auto-added)
__device__ __forceinline__ void gl_lds16(const u16* g, AS3 u16* l) {
  __builtin_amdgcn_global_load_lds((AS1 void*)g, (AS3 void*)l, 16, 0, 0);
}

// ---- fp32 -> bf16 cast, 4 elems/thread ----
__global__ __launch_bounds__(256) void cvt_bf16(const float* __restrict__ s,
                                                u16* __restrict__ d, int n4) {
  int i = blockIdx.x * 256 + threadIdx.x;
  if (i >= n4) return;
  f32x4v f = ((const f32x4v*)s)[i];
  us4 o = { f2b(f[0]), f2b(f[1]), f2b(f[2]), f2b(f[3]) };
  ((us4*)d)[i] = o;
}

// ---- GEMM1: C = X @ Wqkv^T, scatter epilogue into Q [B,H,T,HD], K [B,H,T,HD], Vt [B,H,HD,T]
// X: [8192,1024] bf16 row-major. Wqkv: [3072,1024] bf16 (row = out feature, col = in).
// grid (24, 64), block 256. Tile 128x128, BK=32.
__global__ __launch_bounds__(256) void gemm_qkv(
    const u16* __restrict__ A, const u16* __restrict__ W,
    u16* __restrict__ Qb, u16* __restrict__ Kb, u16* __restrict__ Vt) {
  __shared__ u16 lA[128 * 32];
  __shared__ u16 lB[128 * 32];
  const int tid = threadIdx.x;
  const int lane = tid & 63, wave = tid >> 6;
  const int quad = lane >> 4, l16 = lane & 15;
  const int wr = wave >> 1, wc = wave & 1;
  const int m0 = blockIdx.y * 128;
  const int n0 = blockIdx.x * 128;
  AS3 u16* lA3 = (AS3 u16*)lA;
  AS3 u16* lB3 = (AS3 u16*)lB;
  f32x4 acc[4][4] = {};
  const int c0 = tid, c1 = tid + 256;
  const int ar0 = m0 + (c0 >> 2), ac0 = (c0 & 3) * 8;
  const int ar1 = m0 + (c1 >> 2), ac1 = (c1 & 3) * 8;
  const int br0 = n0 + (c0 >> 2);
  const int br1 = n0 + (c1 >> 2);

  for (int k0 = 0; k0 < 1024; k0 += 32) {
    __syncthreads();
    gl_lds16(A + (size_t)ar0 * 1024 + k0 + ac0, lA3 + wave * 512);
    gl_lds16(A + (size_t)ar1 * 1024 + k0 + ac1, lA3 + 2048 + wave * 512);
    gl_lds16(W + (size_t)br0 * 1024 + k0 + ac0, lB3 + wave * 512);
    gl_lds16(W + (size_t)br1 * 1024 + k0 + ac1, lB3 + 2048 + wave * 512);
    __syncthreads();
    bf16x8 aF[4], bF[4];
#pragma unroll
    for (int mt = 0; mt < 4; mt++)
      aF[mt] = ldfrag(&lA[(wr * 64 + mt * 16 + l16) * 32 + quad * 8]);
#pragma unroll
    for (int nt = 0; nt < 4; nt++)
      bF[nt] = ldfrag(&lB[(wc * 64 + nt * 16 + l16) * 32 + quad * 8]);
#pragma unroll
    for (int mt = 0; mt < 4; mt++)
#pragma unroll
      for (int nt = 0; nt < 4; nt++)
        acc[mt][nt] = mfma16(aF[mt], bF[nt], acc[mt][nt]);
  }

  const int sec = n0 >> 10;  // 0=Q 1=K 2=V (128-col tiles never straddle)
#pragma unroll
  for (int mt = 0; mt < 4; mt++) {
#pragma unroll
    for (int nt = 0; nt < 4; nt++) {
#pragma unroll
      for (int r = 0; r < 4; r++) {
        float v = acc[mt][nt][r];
        int m = m0 + wr * 64 + mt * 16 + quad * 4 + r;
        int n = n0 + wc * 64 + nt * 16 + l16;
        int ns = n & 1023;
        int h = ns >> 6, e = ns & 63;
        int b = m >> 11, t = m & 2047;
        size_t bh = (size_t)b * 16 + h;
        if (sec == 0)      Qb[(bh * 2048 + t) * 64 + e] = f2b(v * 0.125f);  // scale 1/sqrt(64)
        else if (sec == 1) Kb[(bh * 2048 + t) * 64 + e] = f2b(v);
        else               Vt[(bh * 64 + e) * 2048 + t] = f2b(v);
      }
    }
  }
}

// ---- flash attention: Q [B,H,T,64], K [B,H,T,64], Vt [B,H,64,T] -> O [B,T,D] (concat heads)
// grid (32, 64), block 256 (4 waves). Q tile 64 rows (16/wave), KV tile 128.
__global__ __launch_bounds__(256) void attn(
    const u16* __restrict__ Q, const u16* __restrict__ K,
    const u16* __restrict__ Vt, u16* __restrict__ O) {
  __shared__ u16 lK[128 * 72];   // [s][e], pad +8
  __shared__ u16 lV[64 * 136];   // [e][s], pad +8
  __shared__ u16 lP[64 * 136];   // [t][s], pad +8
  const int tid = threadIdx.x;
  const int lane = tid & 63, wave = tid >> 6;
  const int quad = lane >> 4, l16 = lane & 15;
  const int bh = blockIdx.y;
  const int t0 = blockIdx.x * 64;
  const size_t base = (size_t)bh * 2048 * 64;

  const int tq = t0 + wave * 16 + l16;
  bf16x8 aQ0 = ldfrag(Q + base + (size_t)tq * 64 + quad * 8);
  bf16x8 aQ1 = ldfrag(Q + base + (size_t)tq * 64 + 32 + quad * 8);

  float m_i[4] = { -INFINITY, -INFINITY, -INFINITY, -INFINITY };
  float l_i[4] = { 0.f, 0.f, 0.f, 0.f };
  f32x4 o[4] = {};

  const int jdiag = t0 >> 7;
  for (int j = 0; j <= jdiag; j++) {
    const int s0 = j << 7;
    __syncthreads();
#pragma unroll
    for (int i = 0; i < 4; i++) {  // stage K tile 128x64
      int c = tid + i * 256;
      int r = c >> 3, col = (c & 7) * 8;
      *(us8*)&lK[r * 72 + col] = *(const us8*)(K + base + (size_t)(s0 + r) * 64 + col);
    }
#pragma unroll
    for (int i = 0; i < 4; i++) {  // stage Vt tile 64x128
      int c = tid + i * 256;
      int e = c >> 4, col = (c & 15) * 8;
      *(us8*)&lV[e * 136 + col] = *(const us8*)(Vt + base + (size_t)e * 2048 + s0 + col);
    }
    __syncthreads();

    // S = Q K^T : 64x128, per wave 16x128
    f32x4 S[8];
#pragma unroll
    for (int nt = 0; nt < 8; nt++) {
      int sr = nt * 16 + l16;
      f32x4 a = {};
      a = mfma16(aQ0, ldfrag(&lK[sr * 72 + quad * 8]), a);
      a = mfma16(aQ1, ldfrag(&lK[sr * 72 + 32 + quad * 8]), a);
      S[nt] = a;
    }

    if (j == jdiag) {  // causal mask on diagonal tile
#pragma unroll
      for (int nt = 0; nt < 8; nt++) {
        int s = s0 + nt * 16 + l16;
#pragma unroll
        for (int r = 0; r < 4; r++) {
          int t = t0 + wave * 16 + quad * 4 + r;
          if (s > t) S[nt][r] = -INFINITY;
        }
      }
    }

    // online softmax (C-layout: row = quad*4+r, col = lane&15)
#pragma unroll
    for (int r = 0; r < 4; r++) {
      float mx = S[0][r];
#pragma unroll
      for (int nt = 1; nt < 8; nt++) mx = fmaxf(mx, S[nt][r]);
      mx = fmaxf(mx, __shfl_xor(mx, 1));
      mx = fmaxf(mx, __shfl_xor(mx, 2));
      mx = fmaxf(mx, __shfl_xor(mx, 4));
      mx = fmaxf(mx, __shfl_xor(mx, 8));
      float mn = fmaxf(m_i[r], mx);
      float alpha = exp2f((m_i[r] - mn) * 1.44269504f);
      float sum = 0.f;
#pragma unroll
      for (int nt = 0; nt < 8; nt++) {
        float p = exp2f((S[nt][r] - mn) * 1.44269504f);
        S[nt][r] = p;
        sum += p;
      }
      sum += __shfl_xor(sum, 1);
      sum += __shfl_xor(sum, 2);
      sum += __shfl_xor(sum, 4);
      sum += __shfl_xor(sum, 8);
      l_i[r] = l_i[r] * alpha + sum;
      m_i[r] = mn;
#pragma unroll
      for (int ot = 0; ot < 4; ot++) o[ot][r] *= alpha;
    }

    // P -> LDS (C-layout write), then read back in A-layout for PV
#pragma unroll
    for (int nt = 0; nt < 8; nt++)
#pragma unroll
      for (int r = 0; r < 4; r++)
        lP[(wave * 16 + quad * 4 + r) * 136 + nt * 16 + l16] = f2b(S[nt][r]);
    __syncthreads();

#pragma unroll
    for (int ks = 0; ks < 4; ks++) {
      bf16x8 aP = ldfrag(&lP[(wave * 16 + l16) * 136 + ks * 32 + quad * 8]);
#pragma unroll
      for (int ot = 0; ot < 4; ot++) {
        bf16x8 bV = ldfrag(&lV[(ot * 16 + l16) * 136 + ks * 32 + quad * 8]);
        o[ot] = mfma16(aP, bV, o[ot]);
      }
    }
  }

  const int b = bh >> 4, h = bh & 15;
#pragma unroll
  for (int ot = 0; ot < 4; ot++) {
#pragma unroll
    for (int r = 0; r < 4; r++) {
      int t = t0 + wave * 16 + quad * 4 + r;
      O[((size_t)b * 2048 + t) * 1024 + h * 64 + ot * 16 + l16] = f2b(o[ot][r] / l_i[r]);
    }
  }
}

// ---- GEMM2: out = Ao @ Wo^T + bo, fp32 epilogue. grid (8, 64), block 256.
__global__ __launch_bounds__(256) void gemm_out(
    const u16* __restrict__ A, const u16* __restrict__ W,
    const float* __restrict__ bias, float* __restrict__ out) {
  __shared__ u16 lA[128 * 32];
  __shared__ u16 lB[128 * 32];
  const int tid = threadIdx.x;
  const int lane = tid & 63, wave = tid >> 6;
  const int quad = lane >> 4, l16 = lane & 15;
  const int wr = wave >> 1, wc = wave & 1;
  const int m0 = blockIdx.y * 128;
  const int n0 = blockIdx.x * 128;
  AS3 u16* lA3 = (AS3 u16*)lA;
  AS3 u16* lB3 = (AS3 u16*)lB;
  f32x4 acc[4][4] = {};
  const int c0 = tid, c1 = tid + 256;
  const int ar0 = m0 + (c0 >> 2), ac0 = (c0 & 3) * 8;
  const int ar1 = m0 + (c1 >> 2), ac1 = (c1 & 3) * 8;
  const int br0 = n0 + (c0 >> 2);
  const int br1 = n0 + (c1 >> 2);

  for (int k0 = 0; k0 < 1024; k0 += 32) {
    __syncthreads();
    gl_lds16(A + (size_t)ar0 * 1024 + k0 + ac0, lA3 + wave * 512);
    gl_lds16(A + (size_t)ar1 * 1024 + k0 + ac1, lA3 + 2048 + wave * 512);
    gl_lds16(W + (size_t)br0 * 1024 + k0 + ac0, lB3 + wave * 512);
    gl_lds16(W + (size_t)br1 * 1024 + k0 + ac1, lB3 + 2048 + wave * 512);
    __syncthreads();
    bf16x8 aF[4], bF[4];
#pragma unroll
    for (int mt = 0; mt < 4; mt++)
      aF[mt] = ldfrag(&lA[(wr * 64 + mt * 16 + l16) * 32 + quad * 8]);
#pragma unroll
    for (int nt = 0; nt < 4; nt++)
      bF[nt] = ldfrag(&lB[(wc * 64 + nt * 16 + l16) * 32 + quad * 8]);
#pragma unroll
    for (int mt = 0; mt < 4; mt++)
#pragma unroll
      for (int nt = 0; nt < 4; nt++)
        acc[mt][nt] = mfma16(aF[mt], bF[nt], acc[mt][nt]);
  }

#pragma unroll
  for (int mt = 0; mt < 4; mt++) {
#pragma unroll
    for (int nt = 0; nt < 4; nt++) {
#pragma unroll
      for (int r = 0; r < 4; r++) {
        int m = m0 + wr * 64 + mt * 16 + quad * 4 + r;
        int n = n0 + wc * 64 + nt * 16 + l16;
        out[(size_t)m * 1024 + n] = acc[mt][nt][r] + bias[n];
      }
    }
  }
}

extern "C" void kernel_launch(void* const* d_in, const int* in_sizes, int n_in,
                              void* d_out, int out_size, void* d_ws, size_t ws_size,
                              hipStream_t stream) {
  const float* x  = (const float*)d_in[0];
  const float* Wq = (const float*)d_in[1];
  const float* Wk = (const float*)d_in[2];
  const float* Wv = (const float*)d_in[3];
  const float* Wo = (const float*)d_in[4];
  const float* bo = (const float*)d_in[5];
  float* out = (float*)d_out;

  // Workspace layout (u16 elements) — total 40 MB (was 75.5 MB: overflow corrupted
  // the harness's pristine input copies -> post-timing divergence).
  //   ws:  xb/Ao [0, 8388608)          16 MB  (xb dead after gemm_qkv; Ao written by attn)
  //        Wqkv  [8388608, 11534336)    6 MB
  //        Wob   [11534336, 12582912)   2 MB
  //        Qb    [12582912, 20971520)  16 MB
  // d_out used as scratch for K and Vt (both dead before gemm_out writes fp32 result):
  //        Kb = d_out u16 [0, 8388608), Vt = [8388608, 16777216)  — exactly 32 MB.
  u16* ws   = (u16*)d_ws;
  u16* xb   = ws;
  u16* Wqkv = ws + 8388608;
  u16* Wob  = ws + 11534336;
  u16* Qb   = ws + 12582912;
  u16* Ao   = xb;                       // lifetime-disjoint reuse
  u16* Kb   = (u16*)d_out;
  u16* Vt   = Kb + 8388608;

  cvt_bf16<<<8192, 256, 0, stream>>>(x, xb, 2097152);
  cvt_bf16<<<1024, 256, 0, stream>>>(Wq, Wqkv,            262144);
  cvt_bf16<<<1024, 256, 0, stream>>>(Wk, Wqkv + 1048576,  262144);
  cvt_bf16<<<1024, 256, 0, stream>>>(Wv, Wqkv + 2097152,  262144);
  cvt_bf16<<<1024, 256, 0, stream>>>(Wo, Wob,             262144);

  gemm_qkv<<<dim3(24, 64), 256, 0, stream>>>(xb, Wqkv, Qb, Kb, Vt);
  attn<<<dim3(32, 64), 256, 0, stream>>>(Qb, Kb, Vt, Ao);
  gemm_out<<<dim3(8, 64), 256, 0, stream>>>(Ao, Wob, bo, out);
}

// Round 3
// 290.716 us; speedup vs baseline: 1.5548x; 1.5548x over previous
//
#include <hip/hip_runtime.h>
#include <cstdint>
#include <cstddef>

// ---- types ----
typedef unsigned short u16;
typedef float  f32x4  __attribute__((ext_vector_type(4)));
typedef __bf16 bf16x8 __attribute__((ext_vector_type(8)));
typedef unsigned short us8 __attribute__((ext_vector_type(8)));
typedef unsigned short us4 __attribute__((ext_vector_type(4)));
typedef float  f32x4v __attribute__((ext_vector_type(4)));

#define AS1 __attribute__((address_space(1)))
#define AS3 __attribute__((address_space(3)))

// fp32 -> bf16 round-to-nearest-even
__device__ __forceinline__ u16 f2b(float f) {
  unsigned u = __float_as_uint(f);
  u += 0x7FFFu + ((u >> 16) & 1u);
  return (u16)(u >> 16);
}

__device__ __forceinline__ bf16x8 ldfrag(const u16* p) {
  us8 v = *(const us8*)p;
  return __builtin_bit_cast(bf16x8, v);
}

__device__ __forceinline__ f32x4 mfma16(bf16x8 a, bf16x8 b, f32x4 c) {
  return __builtin_amdgcn_mfma_f32_16x16x32_bf16(a, b, c, 0, 0, 0);
}

// async global->LDS, 16B per lane; lds base must be wave-uniform (lane*16 auto-added)
__device__ __forceinline__ void gl_lds16(const u16* g, AS3 u16* l) {
  __builtin_amdgcn_global_load_lds((AS1 void*)g, (AS3 void*)l, 16, 0, 0);
}

// ---- fp32 -> bf16 cast, 4 elems/thread ----
__global__ __launch_bounds__(256) void cvt_bf16(const float* __restrict__ s,
                                                u16* __restrict__ d, int n4) {
  int i = blockIdx.x * 256 + threadIdx.x;
  if (i >= n4) return;
  f32x4v f = ((const f32x4v*)s)[i];
  us4 o = { f2b(f[0]), f2b(f[1]), f2b(f[2]), f2b(f[3]) };
  ((us4*)d)[i] = o;
}

// ---- GEMM1: C = X @ Wqkv^T, scatter epilogue into Q [B,H,T,HD], K [B,H,T,HD], Vt [B,H,HD,T]
// For the V section the MFMA operands are swapped so C is transposed in-register and
// the Vt store coalesces (lanes -> consecutive t) instead of a stride-2048 scatter.
__global__ __launch_bounds__(256) void gemm_qkv(
    const u16* __restrict__ A, const u16* __restrict__ W,
    u16* __restrict__ Qb, u16* __restrict__ Kb, u16* __restrict__ Vt) {
  __shared__ u16 lA[128 * 32];
  __shared__ u16 lB[128 * 32];
  const int tid = threadIdx.x;
  const int lane = tid & 63, wave = tid >> 6;
  const int quad = lane >> 4, l16 = lane & 15;
  const int wr = wave >> 1, wc = wave & 1;
  const int m0 = blockIdx.y * 128;
  const int n0 = blockIdx.x * 128;
  const int sec = n0 >> 10;  // 0=Q 1=K 2=V
  AS3 u16* lA3 = (AS3 u16*)lA;
  AS3 u16* lB3 = (AS3 u16*)lB;
  f32x4 acc[4][4] = {};
  const int c0 = tid, c1 = tid + 256;
  const int ar0 = m0 + (c0 >> 2), ac0 = (c0 & 3) * 8;
  const int ar1 = m0 + (c1 >> 2), ac1 = (c1 & 3) * 8;
  const int br0 = n0 + (c0 >> 2);
  const int br1 = n0 + (c1 >> 2);

  for (int k0 = 0; k0 < 1024; k0 += 32) {
    __syncthreads();
    gl_lds16(A + (size_t)ar0 * 1024 + k0 + ac0, lA3 + wave * 512);
    gl_lds16(A + (size_t)ar1 * 1024 + k0 + ac1, lA3 + 2048 + wave * 512);
    gl_lds16(W + (size_t)br0 * 1024 + k0 + ac0, lB3 + wave * 512);
    gl_lds16(W + (size_t)br1 * 1024 + k0 + ac1, lB3 + 2048 + wave * 512);
    __syncthreads();
    bf16x8 aF[4], bF[4];
#pragma unroll
    for (int mt = 0; mt < 4; mt++)
      aF[mt] = ldfrag(&lA[(wr * 64 + mt * 16 + l16) * 32 + quad * 8]);
#pragma unroll
    for (int nt = 0; nt < 4; nt++)
      bF[nt] = ldfrag(&lB[(wc * 64 + nt * 16 + l16) * 32 + quad * 8]);
    if (sec != 2) {
#pragma unroll
      for (int mt = 0; mt < 4; mt++)
#pragma unroll
        for (int nt = 0; nt < 4; nt++)
          acc[mt][nt] = mfma16(aF[mt], bF[nt], acc[mt][nt]);
    } else {  // transposed accumulate: C[n][m]
#pragma unroll
      for (int mt = 0; mt < 4; mt++)
#pragma unroll
        for (int nt = 0; nt < 4; nt++)
          acc[mt][nt] = mfma16(bF[nt], aF[mt], acc[mt][nt]);
    }
  }

  if (sec != 2) {
#pragma unroll
    for (int mt = 0; mt < 4; mt++) {
#pragma unroll
      for (int nt = 0; nt < 4; nt++) {
#pragma unroll
        for (int r = 0; r < 4; r++) {
          float v = acc[mt][nt][r];
          int m = m0 + wr * 64 + mt * 16 + quad * 4 + r;
          int n = n0 + wc * 64 + nt * 16 + l16;
          int ns = n & 1023;
          int h = ns >> 6, e = ns & 63;
          int b = m >> 11, t = m & 2047;
          size_t bh = (size_t)b * 16 + h;
          if (sec == 0) Qb[(bh * 2048 + t) * 64 + e] = f2b(v * 0.125f);  // 1/sqrt(64)
          else          Kb[(bh * 2048 + t) * 64 + e] = f2b(v);
        }
      }
    }
  } else {
#pragma unroll
    for (int mt = 0; mt < 4; mt++) {
#pragma unroll
      for (int nt = 0; nt < 4; nt++) {
#pragma unroll
        for (int r = 0; r < 4; r++) {
          float v = acc[mt][nt][r];
          int n = n0 + wc * 64 + nt * 16 + quad * 4 + r;  // feature (row of C)
          int m = m0 + wr * 64 + mt * 16 + l16;           // token (col of C)
          int ns = n & 1023;
          int h = ns >> 6, e = ns & 63;
          int b = m >> 11, t = m & 2047;
          size_t bh = (size_t)b * 16 + h;
          Vt[(bh * 64 + e) * 2048 + t] = f2b(v);          // lanes -> consecutive t
        }
      }
    }
  }
}

// ---- flash attention v2: S computed transposed (A=K, B=Q) so softmax state is
// one scalar per lane; P^T->B-layout via wave-private LDS chunk buffer (no barrier).
// Q-tile 128 rows, 8 waves (wave w owns rows t0+w*16+l16), KV tile 128.
// grid (bh=64, qb=16) — same-bh blocks land on one XCD; qb reversed for balance.
__global__ __launch_bounds__(512, 4) void attn(
    const u16* __restrict__ Q, const u16* __restrict__ K,
    const u16* __restrict__ Vt, u16* __restrict__ O) {
  __shared__ u16 lK[128 * 72];     // [s][e] pad+8
  __shared__ u16 lV[64 * 136];     // [e][s] pad+8
  __shared__ u16 lP[8 * 16 * 40];  // per-wave [16t][32s pad+8]
  const int tid = threadIdx.x;
  const int lane = tid & 63, wave = tid >> 6;
  const int quad = lane >> 4, l16 = lane & 15;
  const int bh = blockIdx.x;
  const int qb = 15 - (int)blockIdx.y;
  const int t0 = qb << 7;
  const size_t base = (size_t)bh * (2048 * 64);
  u16* lPw = lP + wave * 640;

  const int tq = t0 + wave * 16 + l16;
  const bf16x8 qF0 = ldfrag(Q + base + (size_t)tq * 64 + quad * 8);
  const bf16x8 qF1 = ldfrag(Q + base + (size_t)tq * 64 + 32 + quad * 8);

  float m_i = -INFINITY, l_i = 0.f;
  f32x4 o[4] = {};

  for (int j = 0; j <= qb; j++) {
    const int s0 = j << 7;
    __syncthreads();
#pragma unroll
    for (int i = 0; i < 2; i++) {  // stage K tile 128x64 (coalesced 16B)
      int c = tid + i * 512;
      int r = c >> 3, col = (c & 7) * 8;
      *(us8*)&lK[r * 72 + col] = *(const us8*)(K + base + (size_t)(s0 + r) * 64 + col);
    }
#pragma unroll
    for (int i = 0; i < 2; i++) {  // stage Vt tile 64x128
      int c = tid + i * 512;
      int e = c >> 4, col = (c & 15) * 8;
      *(us8*)&lV[e * 136 + col] = *(const us8*)(Vt + base + (size_t)e * 2048 + s0 + col);
    }
    __syncthreads();

    // S^T = K·Q^T : C[s][t], lane owns col t=tq, rows s = nt*16+quad*4+r
    f32x4 S[8];
#pragma unroll
    for (int nt = 0; nt < 8; nt++) {
      int sr = nt * 16 + l16;
      f32x4 a = {};
      a = mfma16(ldfrag(&lK[sr * 72 + quad * 8]), qF0, a);
      a = mfma16(ldfrag(&lK[sr * 72 + 32 + quad * 8]), qF1, a);
      S[nt] = a;
    }

    if (j == qb) {  // causal mask on diagonal tile
#pragma unroll
      for (int nt = 0; nt < 8; nt++)
#pragma unroll
        for (int r = 0; r < 4; r++) {
          int s = s0 + nt * 16 + quad * 4 + r;
          if (s > tq) S[nt][r] = -INFINITY;
        }
    }

    // online softmax: in-lane reduce over 32 s-values + 2 cross-quad shuffles
    f32x4 m4 = S[0];
#pragma unroll
    for (int nt = 1; nt < 8; nt++)
#pragma unroll
      for (int r = 0; r < 4; r++) m4[r] = fmaxf(m4[r], S[nt][r]);
    float mx = fmaxf(fmaxf(m4[0], m4[1]), fmaxf(m4[2], m4[3]));
    mx = fmaxf(mx, __shfl_xor(mx, 16));
    mx = fmaxf(mx, __shfl_xor(mx, 32));
    float mn = fmaxf(m_i, mx);
    float alpha = exp2f((m_i - mn) * 1.44269504f);
    float sum = 0.f;
#pragma unroll
    for (int nt = 0; nt < 8; nt++)
#pragma unroll
      for (int r = 0; r < 4; r++) {
        float p = exp2f((S[nt][r] - mn) * 1.44269504f);
        S[nt][r] = p;
        sum += p;
      }
    sum += __shfl_xor(sum, 16);
    sum += __shfl_xor(sum, 32);
    l_i = l_i * alpha + sum;
    m_i = mn;
#pragma unroll
    for (int ot = 0; ot < 4; ot++)
#pragma unroll
      for (int r = 0; r < 4; r++) o[ot][r] *= alpha;

    // PV per 32-wide s-chunk: P^T through wave-private LDS (in-order DS, no barrier)
#pragma unroll
    for (int c = 0; c < 4; c++) {
      us4 p0 = { f2b(S[2*c][0]),   f2b(S[2*c][1]),   f2b(S[2*c][2]),   f2b(S[2*c][3]) };
      us4 p1 = { f2b(S[2*c+1][0]), f2b(S[2*c+1][1]), f2b(S[2*c+1][2]), f2b(S[2*c+1][3]) };
      *(us4*)&lPw[l16 * 40 + quad * 4]      = p0;  // s_local = quad*4+r
      *(us4*)&lPw[l16 * 40 + 16 + quad * 4] = p1;  // s_local = 16+quad*4+r
      __asm__ volatile("s_waitcnt lgkmcnt(0)" ::: "memory");
      bf16x8 bP = ldfrag(&lPw[l16 * 40 + quad * 8]);  // B-frag: n=t=l16, k=quad*8+j
#pragma unroll
      for (int ot = 0; ot < 4; ot++)
        o[ot] = mfma16(ldfrag(&lV[(ot * 16 + l16) * 136 + c * 32 + quad * 8]), bP, o[ot]);
    }
  }

  // O^T in C-layout: row e = ot*16+quad*4+r, col t = l16 -> per-lane 8B stores
  const float inv = 1.f / l_i;
  const int b = bh >> 4, h = bh & 15;
#pragma unroll
  for (int ot = 0; ot < 4; ot++) {
    us4 pk = { f2b(o[ot][0] * inv), f2b(o[ot][1] * inv),
               f2b(o[ot][2] * inv), f2b(o[ot][3] * inv) };
    *(us4*)&O[((size_t)b * 2048 + tq) * 1024 + h * 64 + ot * 16 + quad * 4] = pk;
  }
}

// ---- GEMM2: out = Ao @ Wo^T + bo, fp32 epilogue. grid (8, 64), block 256.
__global__ __launch_bounds__(256) void gemm_out(
    const u16* __restrict__ A, const u16* __restrict__ W,
    const float* __restrict__ bias, float* __restrict__ out) {
  __shared__ u16 lA[128 * 32];
  __shared__ u16 lB[128 * 32];
  const int tid = threadIdx.x;
  const int lane = tid & 63, wave = tid >> 6;
  const int quad = lane >> 4, l16 = lane & 15;
  const int wr = wave >> 1, wc = wave & 1;
  const int m0 = blockIdx.y * 128;
  const int n0 = blockIdx.x * 128;
  AS3 u16* lA3 = (AS3 u16*)lA;
  AS3 u16* lB3 = (AS3 u16*)lB;
  f32x4 acc[4][4] = {};
  const int c0 = tid, c1 = tid + 256;
  const int ar0 = m0 + (c0 >> 2), ac0 = (c0 & 3) * 8;
  const int ar1 = m0 + (c1 >> 2), ac1 = (c1 & 3) * 8;
  const int br0 = n0 + (c0 >> 2);
  const int br1 = n0 + (c1 >> 2);

  for (int k0 = 0; k0 < 1024; k0 += 32) {
    __syncthreads();
    gl_lds16(A + (size_t)ar0 * 1024 + k0 + ac0, lA3 + wave * 512);
    gl_lds16(A + (size_t)ar1 * 1024 + k0 + ac1, lA3 + 2048 + wave * 512);
    gl_lds16(W + (size_t)br0 * 1024 + k0 + ac0, lB3 + wave * 512);
    gl_lds16(W + (size_t)br1 * 1024 + k0 + ac1, lB3 + 2048 + wave * 512);
    __syncthreads();
    bf16x8 aF[4], bF[4];
#pragma unroll
    for (int mt = 0; mt < 4; mt++)
      aF[mt] = ldfrag(&lA[(wr * 64 + mt * 16 + l16) * 32 + quad * 8]);
#pragma unroll
    for (int nt = 0; nt < 4; nt++)
      bF[nt] = ldfrag(&lB[(wc * 64 + nt * 16 + l16) * 32 + quad * 8]);
#pragma unroll
    for (int mt = 0; mt < 4; mt++)
#pragma unroll
      for (int nt = 0; nt < 4; nt++)
        acc[mt][nt] = mfma16(aF[mt], bF[nt], acc[mt][nt]);
  }

#pragma unroll
  for (int mt = 0; mt < 4; mt++) {
#pragma unroll
    for (int nt = 0; nt < 4; nt++) {
#pragma unroll
      for (int r = 0; r < 4; r++) {
        int m = m0 + wr * 64 + mt * 16 + quad * 4 + r;
        int n = n0 + wc * 64 + nt * 16 + l16;
        out[(size_t)m * 1024 + n] = acc[mt][nt][r] + bias[n];
      }
    }
  }
}

extern "C" void kernel_launch(void* const* d_in, const int* in_sizes, int n_in,
                              void* d_out, int out_size, void* d_ws, size_t ws_size,
                              hipStream_t stream) {
  const float* x  = (const float*)d_in[0];
  const float* Wq = (const float*)d_in[1];
  const float* Wk = (const float*)d_in[2];
  const float* Wv = (const float*)d_in[3];
  const float* Wo = (const float*)d_in[4];
  const float* bo = (const float*)d_in[5];
  float* out = (float*)d_out;

  // ws (u16 elems), 40 MB total: xb/Ao | Wqkv | Wob | Qb.
  // d_out doubles as scratch for Kb+Vt (dead before gemm_out's fp32 write).
  u16* ws   = (u16*)d_ws;
  u16* xb   = ws;
  u16* Wqkv = ws + 8388608;
  u16* Wob  = ws + 11534336;
  u16* Qb   = ws + 12582912;
  u16* Ao   = xb;                       // lifetime-disjoint reuse
  u16* Kb   = (u16*)d_out;
  u16* Vt   = Kb + 8388608;

  cvt_bf16<<<8192, 256, 0, stream>>>(x, xb, 2097152);
  cvt_bf16<<<1024, 256, 0, stream>>>(Wq, Wqkv,            262144);
  cvt_bf16<<<1024, 256, 0, stream>>>(Wk, Wqkv + 1048576,  262144);
  cvt_bf16<<<1024, 256, 0, stream>>>(Wv, Wqkv + 2097152,  262144);
  cvt_bf16<<<1024, 256, 0, stream>>>(Wo, Wob,             262144);

  gemm_qkv<<<dim3(24, 64), 256, 0, stream>>>(xb, Wqkv, Qb, Kb, Vt);
  attn<<<dim3(64, 16), 512, 0, stream>>>(Qb, Kb, Vt, Ao);
  gemm_out<<<dim3(8, 64), 256, 0, stream>>>(Ao, Wob, bo, out);
}